// Round 8
// baseline (45.520 us; speedup 1.0000x reference)
//
#include <hip/hip_runtime.h>

#define CH 85            // channels per anchor in add_sigmoid
#define BATCH 16
#define BLOCK 256
#define ROWS 192         // anchors staged per block; LDS = 192*85*4 = 65280 B
#define F4_PER_BLOCK (ROWS * CH / 4)   // 4080 float4 per block tile
#define FBLOCK 256

// ---------- Kernel 1: stream rows to LDS, conf BCE + wave-coop fore ----------
__global__ void __launch_bounds__(BLOCK)
multibox_main(const float* __restrict__ add_sigmoid,
              const float* __restrict__ loc_t,
              const float* __restrict__ conf_t,
              const float* __restrict__ scale_t,
              const int*   __restrict__ cls_t,
              const unsigned char* __restrict__ fore_m,
              const unsigned char* __restrict__ back_m,
              float* __restrict__ partials,
              int n)
{
    __shared__ float lds[ROWS * CH];     // 65280 B
    __shared__ float wsum[BLOCK / 64];

    // mask dtype detection: numpy bool (1B) vs int32 (4B). back = !fore, so
    // u8 storage has fore^back == 1 at byte offsets 1..3; i32 storage has 0s.
    const bool is_u8 =
        (((fore_m[1] ^ back_m[1]) | (fore_m[2] ^ back_m[2]) | (fore_m[3] ^ back_m[3])) & 1) != 0;
    const int* fore_i32 = (const int*)fore_m;

    const int lane = threadIdx.x & 63;
    const int wid  = threadIdx.x >> 6;
    const int r0   = blockIdx.x * ROWS;               // first anchor of this tile

    // ---- stage 192 rows (65280 B) coalesced float4 -> LDS ----
    {
        const float4* src = (const float4*)add_sigmoid;
        float4* dst = (float4*)lds;
        const long long total_f4 = (long long)n * CH / 4;   // n*CH divisible by 4 here
        const long long f4_base  = (long long)blockIdx.x * F4_PER_BLOCK;
        #pragma unroll
        for (int k = threadIdx.x; k < F4_PER_BLOCK; k += BLOCK) {
            const long long g = f4_base + k;
            if (g < total_f4) dst[k] = src[g];
        }
    }
    __syncthreads();

    // ---- conf BCE from LDS (fore + back == 1 for every anchor) ----
    const int r = threadIdx.x;            // local row; threads 192..255 idle here
    const int i = r0 + r;                 // global anchor
    float acc = 0.f;
    bool fore_b = false;
    if (r < ROWS && i < n) {
        fore_b = is_u8 ? (fore_m[i] != 0) : (fore_i32[i] != 0);
        const float cp  = lds[CH * r + 4];
        const float t   = conf_t[i];
        const float lp  = __logf(cp);
        const float l1p = __logf(1.f - cp);
        acc = -__builtin_fmaf(t, lp - l1p, l1p);
    }

    // ---- wave-cooperative fore anchors, rows read from LDS ----
    unsigned long long m = __ballot(fore_b);
    const int wave_row0 = wid * 64;       // local row owned by lane 0 of this wave
    while (m) {
        const int src = (int)__ffsll((long long)m) - 1;
        m &= m - 1;
        const int ar = wave_row0 + src;   // local row of the fore anchor
        const int a  = r0 + ar;           // global anchor
        const int k  = cls_t[a];          // broadcast load

        float c = 0.f;
        const float p = lds[CH * ar + lane];          // channels 0..63
        if (lane < 4) {
            const float d = loc_t[4 * (size_t)a + lane] - p;
            c = scale_t[a] * 0.5f * d * d;
        } else if (lane >= 5) {                       // classes 0..58
            c = (lane - 5 == k) ? -__logf(p) : -__logf(1.f - p);
        }
        if (lane < CH - 64) {                         // channels 64..84 -> classes 59..79
            const float p2 = lds[CH * ar + 64 + lane];
            c += (lane + 59 == k) ? -__logf(p2) : -__logf(1.f - p2);
        }
        acc += c;
    }

    // ---- block reduction -> one partial per block ----
    #pragma unroll
    for (int off = 32; off > 0; off >>= 1)
        acc += __shfl_down(acc, off, 64);
    if (lane == 0) wsum[wid] = acc;
    __syncthreads();
    if (threadIdx.x == 0)
        partials[blockIdx.x] = wsum[0] + wsum[1] + wsum[2] + wsum[3];
}

// ---------- Kernel 2: single-block finalize ----------
__global__ void __launch_bounds__(FBLOCK)
multibox_finalize(const float* __restrict__ partials, float* __restrict__ out, int g)
{
    float acc = 0.f;
    for (int j = threadIdx.x; j < g; j += FBLOCK) acc += partials[j];
    #pragma unroll
    for (int off = 32; off > 0; off >>= 1)
        acc += __shfl_down(acc, off, 64);
    __shared__ float wsum[FBLOCK / 64];
    const int lane = threadIdx.x & 63, wid = threadIdx.x >> 6;
    if (lane == 0) wsum[wid] = acc;
    __syncthreads();
    if (threadIdx.x == 0)
        out[0] = (wsum[0] + wsum[1] + wsum[2] + wsum[3]) * (1.f / BATCH);
}

extern "C" void kernel_launch(void* const* d_in, const int* in_sizes, int n_in,
                              void* d_out, int out_size, void* d_ws, size_t ws_size,
                              hipStream_t stream) {
    const float* add_sigmoid = (const float*)d_in[0];
    const float* loc_t       = (const float*)d_in[1];
    const float* conf_t      = (const float*)d_in[2];
    const float* scale_t     = (const float*)d_in[3];
    const int*   cls_t       = (const int*)d_in[4];
    const unsigned char* fore_m = (const unsigned char*)d_in[5];
    const unsigned char* back_m = (const unsigned char*)d_in[6];
    float* out = (float*)d_out;

    const int n    = in_sizes[2];                   // conf_t count = B*P
    const int grid = (n + ROWS - 1) / ROWS;         // 1896 tiles

    float* partials = (float*)d_ws;                 // grid floats, overwritten each call

    multibox_main<<<grid, BLOCK, 0, stream>>>(
        add_sigmoid, loc_t, conf_t, scale_t, cls_t, fore_m, back_m, partials, n);
    multibox_finalize<<<1, FBLOCK, 0, stream>>>(partials, out, grid);
}

// Round 9
// 19.740 us; speedup vs baseline: 2.3059x; 2.3059x over previous
//
#include <hip/hip_runtime.h>

#define CH 85            // channels per anchor in add_sigmoid
#define BATCH 16
#define BLOCK 256
#define FBLOCK 1024

// ---------- Kernel 1: dense conf BCE + wave-cooperative fore terms ----------
// __launch_bounds__(256, 6): cap VGPRs at 512/6 = 85 so 6 blocks (24 waves)
// fit per CU -> all 5688 waves of the grid co-resident in a single round.
__global__ void __launch_bounds__(BLOCK, 6)
multibox_main(const float* __restrict__ add_sigmoid,
              const float* __restrict__ loc_t,
              const float* __restrict__ conf_t,
              const float* __restrict__ scale_t,
              const int*   __restrict__ cls_t,
              const unsigned char* __restrict__ fore_m,
              const unsigned char* __restrict__ back_m,
              float* __restrict__ partials,
              int n)
{
    // mask dtype detection: numpy bool (1B) vs int32 (4B). back = !fore, so
    // u8 storage has fore^back == 1 at byte offsets 1..3; i32 storage has 0s.
    const bool is_u8 =
        (((fore_m[1] ^ back_m[1]) | (fore_m[2] ^ back_m[2]) | (fore_m[3] ^ back_m[3])) & 1) != 0;
    const int* fore_i32 = (const int*)fore_m;

    const int i         = blockIdx.x * BLOCK + threadIdx.x;
    const int lane      = threadIdx.x & 63;
    const int wave_base = blockIdx.x * BLOCK + (threadIdx.x & ~63);

    float acc = 0.f;
    bool fore_b = false;
    if (i < n) {
        fore_b = is_u8 ? (fore_m[i] != 0) : (fore_i32[i] != 0);
        // conf BCE (fore + back == 1): -(l1p + t*(lp - l1p))
        const float cp  = add_sigmoid[(size_t)i * CH + 4];
        const float t   = conf_t[i];
        const float lp  = __logf(cp);
        const float l1p = __logf(1.f - cp);
        acc = -__builtin_fmaf(t, lp - l1p, l1p);
    }

    // ---- wave-cooperative fore anchors (index by arithmetic, no shfl) ----
    unsigned long long m = __ballot(fore_b);
    while (m) {
        const int src = (int)__ffsll((long long)m) - 1;
        m &= m - 1;
        const int a = wave_base + src;            // lane src owns anchor wave_base+src
        const float* base = add_sigmoid + (size_t)a * CH;
        const int k = cls_t[a];                   // broadcast load

        float c = 0.f;
        const float p = base[lane];               // channels 0..63
        if (lane < 4) {
            const float d = loc_t[4 * (size_t)a + lane] - p;
            c = scale_t[a] * 0.5f * d * d;
        } else if (lane >= 5) {                   // classes 0..58
            c = (lane - 5 == k) ? -__logf(p) : -__logf(1.f - p);
        }
        if (lane < CH - 64) {                     // channels 64..84 -> classes 59..79
            const float p2 = base[lane + 64];
            c += (lane + 59 == k) ? -__logf(p2) : -__logf(1.f - p2);
        }
        acc += c;
    }

    // ---- block reduction -> one partial per block, no atomics ----
    #pragma unroll
    for (int off = 32; off > 0; off >>= 1)
        acc += __shfl_down(acc, off, 64);
    __shared__ float wsum[BLOCK / 64];
    const int wid = threadIdx.x >> 6;
    if (lane == 0) wsum[wid] = acc;
    __syncthreads();
    if (threadIdx.x == 0)
        partials[blockIdx.x] = wsum[0] + wsum[1] + wsum[2] + wsum[3];
}

// ---------- Kernel 2: single-block finalize ----------
__global__ void __launch_bounds__(FBLOCK)
multibox_finalize(const float* __restrict__ partials, float* __restrict__ out, int g)
{
    float acc = 0.f;
    for (int j = threadIdx.x; j < g; j += FBLOCK) acc += partials[j];
    #pragma unroll
    for (int off = 32; off > 0; off >>= 1)
        acc += __shfl_down(acc, off, 64);
    __shared__ float wsum[FBLOCK / 64];
    const int lane = threadIdx.x & 63, wid = threadIdx.x >> 6;
    if (lane == 0) wsum[wid] = acc;
    __syncthreads();
    if (threadIdx.x == 0) {
        float s = 0.f;
        #pragma unroll
        for (int w = 0; w < FBLOCK / 64; ++w) s += wsum[w];
        out[0] = s * (1.f / BATCH);
    }
}

extern "C" void kernel_launch(void* const* d_in, const int* in_sizes, int n_in,
                              void* d_out, int out_size, void* d_ws, size_t ws_size,
                              hipStream_t stream) {
    const float* add_sigmoid = (const float*)d_in[0];
    const float* loc_t       = (const float*)d_in[1];
    const float* conf_t      = (const float*)d_in[2];
    const float* scale_t     = (const float*)d_in[3];
    const int*   cls_t       = (const int*)d_in[4];
    const unsigned char* fore_m = (const unsigned char*)d_in[5];
    const unsigned char* back_m = (const unsigned char*)d_in[6];
    float* out = (float*)d_out;

    const int n    = in_sizes[2];                  // conf_t count = B*P
    const int grid = (n + BLOCK - 1) / BLOCK;      // 1422

    float* partials = (float*)d_ws;                // grid floats, overwritten each call

    multibox_main<<<grid, BLOCK, 0, stream>>>(
        add_sigmoid, loc_t, conf_t, scale_t, cls_t, fore_m, back_m, partials, n);
    multibox_finalize<<<1, FBLOCK, 0, stream>>>(partials, out, grid);
}